// Round 6
// baseline (146.950 us; speedup 1.0000x reference)
//
#include <hip/hip_runtime.h>
#include <math.h>

typedef unsigned short u16;
typedef __attribute__((ext_vector_type(8))) short short8;
typedef __attribute__((ext_vector_type(4))) float f32x4;
typedef __attribute__((ext_vector_type(4))) int i32x4;
typedef __attribute__((ext_vector_type(4))) u16 u16x4;

#define AS1 __attribute__((address_space(1)))
#define AS3 __attribute__((address_space(3)))

__device__ inline u16 f2bf(float f){
  union { float f; unsigned int u; } x; x.f = f;
  unsigned int r = x.u + 0x7fffu + ((x.u >> 16) & 1u);
  return (u16)(r >> 16);
}

// ---------------- fused prep: LayerNorm (blocks 0..2047) + 4 weight converts ----------------
__global__ __launch_bounds__(256) void prep_kernel(
    const float* __restrict__ x, const float* __restrict__ g, const float* __restrict__ b,
    u16* __restrict__ xn,
    const float* __restrict__ qkv_w, u16* __restrict__ qkvw_b,
    const float* __restrict__ out_w, u16* __restrict__ outw_b,
    const float* __restrict__ w1,    u16* __restrict__ w1_b,
    const float* __restrict__ w2,    u16* __restrict__ w2_b)
{
  const int tid = threadIdx.x;
  int bid = blockIdx.x;
  if (bid < 2048){
    const int row = bid;
    float4 v = *(const float4*)(x + (size_t)row*1024 + tid*4);
    float s  = v.x + v.y + v.z + v.w;
    float ss = v.x*v.x + v.y*v.y + v.z*v.z + v.w*v.w;
    #pragma unroll
    for (int off = 32; off; off >>= 1){
      s  += __shfl_xor(s,  off, 64);
      ss += __shfl_xor(ss, off, 64);
    }
    __shared__ float red[8];
    const int wid = tid >> 6;
    if ((tid & 63) == 0){ red[wid] = s; red[4+wid] = ss; }
    __syncthreads();
    float S  = red[0]+red[1]+red[2]+red[3];
    float SS = red[4]+red[5]+red[6]+red[7];
    float mu  = S * (1.0f/1024.0f);
    float var = SS * (1.0f/1024.0f) - mu*mu;
    float rs  = rsqrtf(var + 1e-5f);
    float4 gv = *(const float4*)(g + tid*4);
    float4 bv = *(const float4*)(b + tid*4);
    u16x4 pk;
    pk.x = f2bf((v.x-mu)*rs*gv.x + bv.x);
    pk.y = f2bf((v.y-mu)*rs*gv.y + bv.y);
    pk.z = f2bf((v.z-mu)*rs*gv.z + bv.z);
    pk.w = f2bf((v.w-mu)*rs*gv.w + bv.w);
    *(u16x4*)(xn + (size_t)row*1024 + tid*4) = pk;
    return;
  }
  bid -= 2048;
  const float* src; u16* dst;
  if (bid < 3072){ src = qkv_w; dst = qkvw_b; }
  else if (bid < 3072+1024){ src = out_w; dst = outw_b; bid -= 3072; }
  else if (bid < 3072+1024+4096){ src = w1; dst = w1_b; bid -= 3072+1024; }
  else { src = w2; dst = w2_b; bid -= 3072+1024+4096; }
  const size_t i = ((size_t)bid*256 + tid) * 4;
  float4 v = *(const float4*)(src + i);
  u16x4 pk;
  pk.x = f2bf(v.x); pk.y = f2bf(v.y); pk.z = f2bf(v.z); pk.w = f2bf(v.w);
  *(u16x4*)(dst + i) = pk;
}

// ---------------- GEMM: 128xBN block, 256 thr / 4 waves, BK=32, 4-buffer deep pipeline ----
// C[M,N] = A[M,K] * B[N,K]^T. global_load_lds width=16 into linear LDS; counted vmcnt
// (never drained to 0 in steady state), single raw s_barrier per K-step (T3/T4-lite).
// Bank swizzle: LDS[row][slot] = G[row][slot ^ ((row>>1)&3)] (16B slots), applied on the
// global SOURCE address; reads XOR the same term -> 2-way (free) on both sides.
// BN=128: waves 2x2, wave tile 64x64 (acc 4x4), LDS 64KB -> 2 blk/CU.
// BN=64 : waves 2x2, wave tile 64x32 (acc 4x2), LDS 48KB -> 3 blk/CU.
// EPI 0: bf16 | EPI 1: +resid -> f32+bf16 | EPI 2: +bias,GELU -> bf16 | EPI 4: split-K f32 partial
template<int EPI, int BN>
__global__ __launch_bounds__(256) void gemm_lds(
    const u16* __restrict__ A, const u16* __restrict__ B,
    float* __restrict__ outF, u16* __restrict__ outB,
    const float* __restrict__ bias, const float* __restrict__ resid,
    int M, int N, int K, int nbx, int nwg, int Kc)
{
  constexpr int NR  = BN / 32;             // N-frags per wave
  constexpr int ACH = 2;                   // A chunks (16 rows x 32 cols) per wave per stage
  constexpr int BCH = BN / 64;             // B chunks per wave per stage
  constexpr int L   = ACH + BCH;           // vmcnt increments per stage per wave
  __shared__ u16 As[4][128*32];            // 4 x 8 KB
  __shared__ u16 Bs[4][BN*32];             // 4 x (BN/16) KB
  const int tid = threadIdx.x;
  const int l   = tid & 63;
  const int w   = tid >> 6;                // 0..3
  const int wr  = w >> 1, wc = w & 1;
  const int orig = blockIdx.x;
  const int wgid = (orig & 7) * (nwg >> 3) + (orig >> 3);   // XCD-contiguous (nwg%8==0)
  const int bcol = wgid % nbx, brow = wgid / nbx;
  const int kz = blockIdx.y;
  const int l15 = l & 15, l4 = l >> 4;

  const u16* Ab = A + (size_t)brow*128*K + (size_t)kz*Kc;
  const u16* Bb = B + (size_t)bcol*BN*K  + (size_t)kz*Kc;

  f32x4 acc[4][NR];
  #pragma unroll
  for (int i = 0; i < 4; ++i)
    #pragma unroll
    for (int j = 0; j < NR; ++j)
      acc[i][j] = (f32x4){0.f, 0.f, 0.f, 0.f};

  const int rsub = l >> 2;                         // 0..15 row within chunk
  const int csrc = ((l & 3) ^ ((l >> 3) & 3)) * 8; // swizzled source col group
  const int kop  = ((l4 ^ ((l15 >> 1) & 3)) * 8);  // swizzled read col group
  const int nkt = Kc >> 5;                         // BK=32

  auto stage = [&](int kt, int buf){
    const u16* Ag = Ab + kt*32 + csrc;
    const u16* Bg = Bb + kt*32 + csrc;
    #pragma unroll
    for (int i = 0; i < ACH; ++i){
      const int ca = w*ACH + i;                    // 0..7
      __builtin_amdgcn_global_load_lds(
        (const AS1 void*)(Ag + (size_t)(ca*16 + rsub)*K),
        (AS3 void*)(&As[buf][ca*512]), 16, 0, 0);
    }
    #pragma unroll
    for (int i = 0; i < BCH; ++i){
      const int cb = w*BCH + i;                    // 0..(BN/16-1)
      __builtin_amdgcn_global_load_lds(
        (const AS1 void*)(Bg + (size_t)(cb*16 + rsub)*K),
        (AS3 void*)(&Bs[buf][cb*512]), 16, 0, 0);
    }
  };

  stage(0, 0); stage(1, 1); stage(2, 2);           // prefetch depth 3 (nkt >= 3 always)
  for (int kt = 0; kt < nkt; ++kt){
    // Ensure tile kt's loads (all waves') are done; keep newer stages in flight.
    if (kt < nkt - 2)
      asm volatile("s_waitcnt vmcnt(%0)\n\ts_barrier" :: "n"(2*L) : "memory");
    else if (kt == nkt - 2)
      asm volatile("s_waitcnt vmcnt(%0)\n\ts_barrier" :: "n"(L) : "memory");
    else
      asm volatile("s_waitcnt vmcnt(0)\n\ts_barrier" ::: "memory");
    if (kt + 3 < nkt) stage(kt + 3, (kt + 3) & 3); // overwrites buf read in iter kt-1 (safe past barrier)
    const int cur = kt & 3;
    short8 af[4], bfr[NR];
    #pragma unroll
    for (int i = 0; i < 4; ++i)  af[i]  = *(const short8*)&As[cur][(wr*64 + i*16 + l15)*32 + kop];
    #pragma unroll
    for (int j = 0; j < NR; ++j) bfr[j] = *(const short8*)&Bs[cur][(wc*(BN/2) + j*16 + l15)*32 + kop];
    #pragma unroll
    for (int i = 0; i < 4; ++i)
      #pragma unroll
      for (int j = 0; j < NR; ++j)
        acc[i][j] = __builtin_amdgcn_mfma_f32_16x16x32_bf16(af[i], bfr[j], acc[i][j], 0, 0, 0);
  }

  #pragma unroll
  for (int i = 0; i < 4; ++i){
    #pragma unroll
    for (int j = 0; j < NR; ++j){
      #pragma unroll
      for (int r = 0; r < 4; ++r){
        int row = brow*128 + wr*64 + i*16 + l4*4 + r;
        int col = bcol*BN + wc*(BN/2) + j*16 + l15;
        float v = acc[i][j][r];
        size_t o = (size_t)row * N + col;
        if constexpr (EPI == 0){
          outB[o] = f2bf(v);
        } else if constexpr (EPI == 1){
          v += resid[o];
          outF[o] = v;
          outB[o] = f2bf(v);
        } else if constexpr (EPI == 2){
          v += bias[col];
          v = 0.5f * v * (1.0f + erff(v * 0.70710678118654752f));
          outB[o] = f2bf(v);
        } else {  // EPI == 4: split-K partial
          outF[(size_t)kz * M * N + o] = v;
        }
      }
    }
  }
}

// ---------------- FFN2 split-K=4 reduce: out = p0+p1+p2+p3 + bias + resid ----------------
__global__ __launch_bounds__(256) void reduce_ffn2(const float* __restrict__ p,
                                                   const float* __restrict__ bias,
                                                   const float* __restrict__ resid,
                                                   float* __restrict__ out){
  const size_t s = (size_t)2048*1024;
  const size_t i = ((size_t)blockIdx.x * 256 + threadIdx.x) * 4;
  float4 a0 = *(const float4*)(p + i);
  float4 a1 = *(const float4*)(p + s + i);
  float4 a2 = *(const float4*)(p + 2*s + i);
  float4 a3 = *(const float4*)(p + 3*s + i);
  float4 r  = *(const float4*)(resid + i);
  float4 bb = *(const float4*)(bias + (i & 1023));
  float4 o;
  o.x = a0.x + a1.x + a2.x + a3.x + r.x + bb.x;
  o.y = a0.y + a1.y + a2.y + a3.y + r.y + bb.y;
  o.z = a0.z + a1.z + a2.z + a3.z + r.z + bb.z;
  o.w = a0.w + a1.w + a2.w + a3.w + r.w + bb.w;
  *(float4*)(out + i) = o;
}

// ---------------- Local-window attention ----------------
__global__ __launch_bounds__(256) void attn_kernel(const u16* __restrict__ qkv, u16* __restrict__ attn_out){
  constexpr int S = 2048, D3 = 3072;
  const int qt = blockIdx.x, h = blockIdx.y;
  const int q0 = qt * 64;
  const int tid = threadIdx.x;
  const int l = tid & 63, w = tid >> 6;
  const int l15 = l & 15, l4 = l >> 4;

  __shared__ u16 smem[31232];                    // 62464 B
  u16 (*Qs)[72]  = (u16(*)[72]) (smem);          // 64 x 72
  u16 (*Ks)[72]  = (u16(*)[72]) (smem + 4608);   // 192 x 72
  u16 (*Ps)[200] = (u16(*)[200])(smem + 4608);   // 64 x 200  (aliases Ks, after barrier)
  u16 (*Vt)[200] = (u16(*)[200])(smem + 18432);  // 64 x 200  (V transposed: [d][key])

  #pragma unroll
  for (int i = 0; i < 2; ++i){
    int cid = tid + 256*i; int r = cid >> 3, c = cid & 7;
    *(i32x4*)&Qs[r][c*8] = *(const i32x4*)(qkv + (size_t)(q0 + r)*D3 + h*64 + c*8);
  }
  #pragma unroll
  for (int i = 0; i < 6; ++i){
    int cid = tid + 256*i; int r = cid >> 3, c = cid & 7;
    int kj = q0 - 64 + r;
    i32x4 kv = {0,0,0,0}, vv = {0,0,0,0};
    if (kj >= 0 && kj < S){
      kv = *(const i32x4*)(qkv + (size_t)kj*D3 + 1024 + h*64 + c*8);
      vv = *(const i32x4*)(qkv + (size_t)kj*D3 + 2048 + h*64 + c*8);
    }
    *(i32x4*)&Ks[r][c*8] = kv;
    union { i32x4 v; u16 u[8]; } uu; uu.v = vv;
    #pragma unroll
    for (int j = 0; j < 8; ++j) Vt[c*8 + j][r] = uu.u[j];
  }
  __syncthreads();

  f32x4 sc[12];
  #pragma unroll
  for (int cf = 0; cf < 12; ++cf) sc[cf] = (f32x4){0.f,0.f,0.f,0.f};
  const int ko = l4 * 8;
  short8 a0 = *(const short8*)&Qs[16*w + l15][ko];
  short8 a1 = *(const short8*)&Qs[16*w + l15][32 + ko];
  #pragma unroll
  for (int cf = 0; cf < 12; ++cf){
    short8 b0 = *(const short8*)&Ks[cf*16 + l15][ko];
    short8 b1 = *(const short8*)&Ks[cf*16 + l15][32 + ko];
    sc[cf] = __builtin_amdgcn_mfma_f32_16x16x32_bf16(a0, b0, sc[cf], 0, 0, 0);
    sc[cf] = __builtin_amdgcn_mfma_f32_16x16x32_bf16(a1, b1, sc[cf], 0, 0, 0);
  }
  __syncthreads();

  const float scale = 0.125f;
  #pragma unroll
  for (int r = 0; r < 4; ++r){
    const int qrl = 16*w + l4*4 + r;
    float mx = -1e30f;
    #pragma unroll
    for (int cf = 0; cf < 12; ++cf){
      int j  = cf*16 + l15;
      int kj = q0 - 64 + j;
      bool ok = (j >= qrl) && (j <= qrl + 128) && (kj >= 0) && (kj < S);
      float sv = ok ? sc[cf][r]*scale : -1e30f;
      sc[cf][r] = sv;
      mx = fmaxf(mx, sv);
    }
    #pragma unroll
    for (int off = 1; off < 16; off <<= 1) mx = fmaxf(mx, __shfl_xor(mx, off, 64));
    float sm = 0.f;
    #pragma unroll
    for (int cf = 0; cf < 12; ++cf){
      float pv = __expf(sc[cf][r] - mx);
      sc[cf][r] = pv;
      sm += pv;
    }
    #pragma unroll
    for (int off = 1; off < 16; off <<= 1) sm += __shfl_xor(sm, off, 64);
    float inv = 1.0f / sm;
    #pragma unroll
    for (int cf = 0; cf < 12; ++cf) Ps[qrl][cf*16 + l15] = f2bf(sc[cf][r] * inv);
  }
  __syncthreads();

  f32x4 o[4];
  #pragma unroll
  for (int df = 0; df < 4; ++df) o[df] = (f32x4){0.f,0.f,0.f,0.f};
  #pragma unroll
  for (int kk = 0; kk < 6; ++kk){
    short8 a = *(const short8*)&Ps[16*w + l15][kk*32 + ko];
    #pragma unroll
    for (int df = 0; df < 4; ++df){
      short8 b = *(const short8*)&Vt[df*16 + l15][kk*32 + ko];
      o[df] = __builtin_amdgcn_mfma_f32_16x16x32_bf16(a, b, o[df], 0, 0, 0);
    }
  }
  #pragma unroll
  for (int df = 0; df < 4; ++df){
    #pragma unroll
    for (int r = 0; r < 4; ++r){
      attn_out[(size_t)(q0 + 16*w + l4*4 + r)*1024 + h*64 + df*16 + l15] = f2bf(o[df][r]);
    }
  }
}

extern "C" void kernel_launch(void* const* d_in, const int* in_sizes, int n_in,
                              void* d_out, int out_size, void* d_ws, size_t ws_size,
                              hipStream_t stream)
{
  const float* x     = (const float*)d_in[0];
  const float* qkv_w = (const float*)d_in[1];
  const float* out_w = (const float*)d_in[2];
  const float* ln_g  = (const float*)d_in[3];
  const float* ln_b  = (const float*)d_in[4];
  const float* w1    = (const float*)d_in[5];
  const float* b1    = (const float*)d_in[6];
  const float* w2    = (const float*)d_in[7];
  const float* b2    = (const float*)d_in[8];
  float* out_final = (float*)d_out;

  // Layout: first 33.55 MB is buffers all dead by FFN2 -> reused as 4 f32 partials.
  char* p = (char*)d_ws;
  u16* xn_b   = (u16*)p; p += (size_t)2048*1024*2;   // dead after QKV
  u16* qkv_b  = (u16*)p; p += (size_t)2048*3072*2;   // dead after attn
  u16* attn_b = (u16*)p; p += (size_t)2048*1024*2;   // dead after out-proj
  u16* out_b  = (u16*)p; p += (size_t)2048*1024*2;   // dead after FFN1
  u16* qkvw_b = (u16*)p; p += (size_t)3072*1024*2;   // dead after QKV
  u16* outw_b = (u16*)p; p += (size_t)1024*1024*2;   // dead after out-proj
  u16* w1_b   = (u16*)p; p += (size_t)4096*1024*2;
  u16* w2_b   = (u16*)p; p += (size_t)1024*4096*2;
  float* out_f= (float*)p; p += (size_t)2048*1024*4; // live until reduce
  u16* h_b    = (u16*)p; p += (size_t)2048*4096*2;

  float* partials = (float*)xn_b;  // 4 x 2048x1024 f32 = 33.55 MB over xn..outw (dead by FFN2)

  // fused LN + weight converts (2048 LN blocks + 12288 convert blocks)
  prep_kernel<<<14336, 256, 0, stream>>>(x, ln_g, ln_b, xn_b,
                                         qkv_w, qkvw_b, out_w, outw_b,
                                         w1, w1_b, w2, w2_b);
  // QKV projection: [2048,1024] x [3072,1024]^T -> bf16 [2048,3072]  (16x24 = 384 blocks, all resident)
  gemm_lds<0,128><<<dim3(384), 256, 0, stream>>>(xn_b, qkvw_b, nullptr, qkv_b, nullptr, nullptr,
                                                 2048, 3072, 1024, 24, 384, 1024);
  // local attention -> bf16 [2048,1024]
  attn_kernel<<<dim3(32,16), 256, 0, stream>>>(qkv_b, attn_b);
  // out projection + residual(x): -> out_f32 + out_bf16  (16x16 = 256 blocks, 3/CU LDS cap)
  gemm_lds<1,64><<<dim3(256), 256, 0, stream>>>(attn_b, outw_b, out_f, out_b, nullptr, x,
                                                2048, 1024, 1024, 16, 256, 1024);
  // FFN1 + bias + exact GELU -> h bf16 [2048,4096]  (16x32 = 512 blocks, 2/CU)
  gemm_lds<2,128><<<dim3(512), 256, 0, stream>>>(out_b, w1_b, nullptr, h_b, b1, nullptr,
                                                 2048, 4096, 1024, 32, 512, 1024);
  // FFN2 split-K=4 partials -> f32  (16x8 xy * 4 z = 512 blocks, 2/CU)
  gemm_lds<4,128><<<dim3(128, 4), 256, 0, stream>>>(h_b, w2_b, partials, nullptr, nullptr, nullptr,
                                                    2048, 1024, 4096, 8, 128, 1024);
  // reduce: out = p0+p1+p2+p3 + b2 + out_f
  reduce_ffn2<<<2048, 256, 0, stream>>>(partials, b2, out_f, out_final);
}

// Round 7
// 124.103 us; speedup vs baseline: 1.1841x; 1.1841x over previous
//
#include <hip/hip_runtime.h>
#include <math.h>

typedef unsigned short u16;
typedef __attribute__((ext_vector_type(8))) short short8;
typedef __attribute__((ext_vector_type(4))) float f32x4;
typedef __attribute__((ext_vector_type(4))) int i32x4;
typedef __attribute__((ext_vector_type(4))) u16 u16x4;

#define AS1 __attribute__((address_space(1)))
#define AS3 __attribute__((address_space(3)))

__device__ inline u16 f2bf(float f){
  union { float f; unsigned int u; } x; x.f = f;
  unsigned int r = x.u + 0x7fffu + ((x.u >> 16) & 1u);
  return (u16)(r >> 16);
}
__device__ inline float bf2f(u16 u){
  union { unsigned int u; float f; } x; x.u = ((unsigned int)u) << 16;
  return x.f;
}
// exact-GELU via tanh form (max dev ~3e-4, far below bf16 rounding of h)
__device__ inline float gelu_fast(float v){
  float y = 0.7978845608f * (v + 0.044715f * v * v * v);
  float e = __expf(2.0f * y);
  return v - v / (e + 1.0f);          // = 0.5 v (1 + tanh y); e=inf -> v, e=0 -> 0
}

// ---------------- fused prep: LayerNorm (blocks 0..2047) + 4 weight converts ----------------
__global__ __launch_bounds__(256) void prep_kernel(
    const float* __restrict__ x, const float* __restrict__ g, const float* __restrict__ b,
    u16* __restrict__ xn,
    const float* __restrict__ qkv_w, u16* __restrict__ qkvw_b,
    const float* __restrict__ out_w, u16* __restrict__ outw_b,
    const float* __restrict__ w1,    u16* __restrict__ w1_b,
    const float* __restrict__ w2,    u16* __restrict__ w2_b)
{
  const int tid = threadIdx.x;
  int bid = blockIdx.x;
  if (bid < 2048){
    const int row = bid;
    float4 v = *(const float4*)(x + (size_t)row*1024 + tid*4);
    float s  = v.x + v.y + v.z + v.w;
    float ss = v.x*v.x + v.y*v.y + v.z*v.z + v.w*v.w;
    #pragma unroll
    for (int off = 32; off; off >>= 1){
      s  += __shfl_xor(s,  off, 64);
      ss += __shfl_xor(ss, off, 64);
    }
    __shared__ float red[8];
    const int wid = tid >> 6;
    if ((tid & 63) == 0){ red[wid] = s; red[4+wid] = ss; }
    __syncthreads();
    float S  = red[0]+red[1]+red[2]+red[3];
    float SS = red[4]+red[5]+red[6]+red[7];
    float mu  = S * (1.0f/1024.0f);
    float var = SS * (1.0f/1024.0f) - mu*mu;
    float rs  = rsqrtf(var + 1e-5f);
    float4 gv = *(const float4*)(g + tid*4);
    float4 bv = *(const float4*)(b + tid*4);
    u16x4 pk;
    pk.x = f2bf((v.x-mu)*rs*gv.x + bv.x);
    pk.y = f2bf((v.y-mu)*rs*gv.y + bv.y);
    pk.z = f2bf((v.z-mu)*rs*gv.z + bv.z);
    pk.w = f2bf((v.w-mu)*rs*gv.w + bv.w);
    *(u16x4*)(xn + (size_t)row*1024 + tid*4) = pk;
    return;
  }
  bid -= 2048;
  const float* src; u16* dst;
  if (bid < 3072){ src = qkv_w; dst = qkvw_b; }
  else if (bid < 3072+1024){ src = out_w; dst = outw_b; bid -= 3072; }
  else if (bid < 3072+1024+4096){ src = w1; dst = w1_b; bid -= 3072+1024; }
  else { src = w2; dst = w2_b; bid -= 3072+1024+4096; }
  const size_t i = ((size_t)bid*256 + tid) * 4;
  float4 v = *(const float4*)(src + i);
  u16x4 pk;
  pk.x = f2bf(v.x); pk.y = f2bf(v.y); pk.z = f2bf(v.z); pk.w = f2bf(v.w);
  *(u16x4*)(dst + i) = pk;
}

// ---------------- GEMM: 128xBN block, 256 thr / 4 waves, double-buffered 2-phase ----------
// (R5-proven structure.) C[M,N] = A[M,K] * B[N,K]^T. global_load_lds width=16, linear LDS,
// bank-swizzle via pre-swizzled global SOURCE col: LDS[row][c] = G[row][c ^ (row&7)*8].
// BN=128: waves 2x2, wave tile 64x64 (acc 4x4), LDS 64KB -> 2 blk/CU.
// BN=64 : waves 2x2, wave tile 64x32 (acc 4x2), LDS 48KB -> 3 blk/CU.
// EPI 0: bf16 | EPI 1: +resid(f32) -> bf16 | EPI 2: +bias,GELU -> bf16 | EPI 4: split-K f32 partial
template<int EPI, int BN>
__global__ __launch_bounds__(256) void gemm_lds(
    const u16* __restrict__ A, const u16* __restrict__ B,
    float* __restrict__ outF, u16* __restrict__ outB,
    const float* __restrict__ bias, const float* __restrict__ resid,
    int M, int N, int K, int nbx, int nwg, int Kc)
{
  constexpr int NR = BN / 32;              // N-frags per wave
  __shared__ u16 As[2][128*64];            // 2 x 16 KB
  __shared__ u16 Bs[2][BN*64];             // 2 x (BN/4) KB
  const int tid = threadIdx.x;
  const int l   = tid & 63;
  const int w   = tid >> 6;                // 0..3
  const int wr  = w >> 1, wc = w & 1;
  const int orig = blockIdx.x;
  const int wgid = (orig & 7) * (nwg >> 3) + (orig >> 3);   // XCD-contiguous (nwg%8==0)
  const int bcol = wgid % nbx, brow = wgid / nbx;
  const int kz = blockIdx.y;
  const int l15 = l & 15, l4 = l >> 4;

  const u16* Ab = A + (size_t)brow*128*K + (size_t)kz*Kc;
  const u16* Bb = B + (size_t)bcol*BN*K  + (size_t)kz*Kc;

  f32x4 acc[4][NR];
  #pragma unroll
  for (int i = 0; i < 4; ++i)
    #pragma unroll
    for (int j = 0; j < NR; ++j)
      acc[i][j] = (f32x4){0.f, 0.f, 0.f, 0.f};

  const int rsub = l >> 3;                       // 0..7 (row & 7 of this lane's slot)
  const int csrc = ((l & 7) ^ rsub) * 8;         // swizzled source col (elements)
  const int swz  = (l15 & 7) * 8;                // read-side unswizzle
  const int nkt = Kc >> 6;

  auto stage = [&](int kt, int buf){
    const u16* Ag = Ab + kt*64 + csrc;
    const u16* Bg = Bb + kt*64 + csrc;
    #pragma unroll
    for (int i = 0; i < 4; ++i){
      const int ca = w*4 + i;                    // A chunk 0..15 (8 rows x 64 cols)
      __builtin_amdgcn_global_load_lds(
        (const AS1 void*)(Ag + (size_t)(ca*8 + rsub)*K),
        (AS3 void*)(&As[buf][ca*512]), 16, 0, 0);
    }
    #pragma unroll
    for (int i = 0; i < NR; ++i){
      const int cb = w*NR + i;                   // B chunk 0..(BN/8-1)
      __builtin_amdgcn_global_load_lds(
        (const AS1 void*)(Bg + (size_t)(cb*8 + rsub)*K),
        (AS3 void*)(&Bs[buf][cb*512]), 16, 0, 0);
    }
  };

  stage(0, 0);
  __syncthreads();                               // tile 0 ready
  for (int kt = 0; kt < nkt; ++kt){
    const int cur = kt & 1;
    if (kt + 1 < nkt) stage(kt + 1, cur ^ 1);    // issue next-tile loads FIRST
    #pragma unroll
    for (int ks = 0; ks < 2; ++ks){              // compute current tile
      const int kop = (ks*32 + l4*8) ^ swz;
      short8 af[4], bfr[NR];
      #pragma unroll
      for (int i = 0; i < 4; ++i)  af[i]  = *(const short8*)&As[cur][(wr*64 + i*16 + l15)*64 + kop];
      #pragma unroll
      for (int j = 0; j < NR; ++j) bfr[j] = *(const short8*)&Bs[cur][(wc*(BN/2) + j*16 + l15)*64 + kop];
      #pragma unroll
      for (int i = 0; i < 4; ++i)
        #pragma unroll
        for (int j = 0; j < NR; ++j)
          acc[i][j] = __builtin_amdgcn_mfma_f32_16x16x32_bf16(af[i], bfr[j], acc[i][j], 0, 0, 0);
    }
    __syncthreads();                             // next tile staged + cur reads done
  }

  #pragma unroll
  for (int i = 0; i < 4; ++i){
    #pragma unroll
    for (int j = 0; j < NR; ++j){
      #pragma unroll
      for (int r = 0; r < 4; ++r){
        int row = brow*128 + wr*64 + i*16 + l4*4 + r;
        int col = bcol*BN + wc*(BN/2) + j*16 + l15;
        float v = acc[i][j][r];
        size_t o = (size_t)row * N + col;
        if constexpr (EPI == 0){
          outB[o] = f2bf(v);
        } else if constexpr (EPI == 1){
          v += resid[o];
          outB[o] = f2bf(v);
        } else if constexpr (EPI == 2){
          v += bias[col];
          outB[o] = f2bf(gelu_fast(v));
        } else {  // EPI == 4: split-K partial
          outF[(size_t)kz * M * N + o] = v;
        }
      }
    }
  }
}

// ---------------- FFN2 split-K=4 reduce: out = p0+p1+p2+p3 + bias + resid(bf16) ------------
__global__ __launch_bounds__(256) void reduce_ffn2(const float* __restrict__ p,
                                                   const float* __restrict__ bias,
                                                   const u16* __restrict__ resid_b,
                                                   float* __restrict__ out){
  const size_t s = (size_t)2048*1024;
  const size_t i = ((size_t)blockIdx.x * 256 + threadIdx.x) * 4;
  float4 a0 = *(const float4*)(p + i);
  float4 a1 = *(const float4*)(p + s + i);
  float4 a2 = *(const float4*)(p + 2*s + i);
  float4 a3 = *(const float4*)(p + 3*s + i);
  u16x4 rb  = *(const u16x4*)(resid_b + i);
  float4 bb = *(const float4*)(bias + (i & 1023));
  float4 o;
  o.x = a0.x + a1.x + a2.x + a3.x + bf2f(rb.x) + bb.x;
  o.y = a0.y + a1.y + a2.y + a3.y + bf2f(rb.y) + bb.y;
  o.z = a0.z + a1.z + a2.z + a3.z + bf2f(rb.z) + bb.z;
  o.w = a0.w + a1.w + a2.w + a3.w + bf2f(rb.w) + bb.w;
  *(float4*)(out + i) = o;
}

// ---------------- Local-window attention ----------------
// K staged via global_load_lds into linear [192][64] with source swizzle (row&7);
// K rows outside [0,S) read adjacent ws garbage but are masked AFTER QK^T (value replaced).
// V keeps conditional zero-fill (P=0 x garbage-inf would NaN through MFMA).
__global__ __launch_bounds__(256) void attn_kernel(const u16* __restrict__ qkv, u16* __restrict__ attn_out){
  constexpr int S = 2048, D3 = 3072;
  const int qt = blockIdx.x, h = blockIdx.y;
  const int q0 = qt * 64;
  const int tid = threadIdx.x;
  const int l = tid & 63, w = tid >> 6;
  const int l15 = l & 15, l4 = l >> 4;

  __shared__ u16 smem[29696];                    // 59392 B
  u16 (*Qs)[72]  = (u16(*)[72]) (smem);          // 64 x 72 (padded, reg-staged)
  u16 *Ks        = smem + 4608;                  // 192 x 64 linear (gload_lds, swizzled)
  u16 (*Ps)[200] = (u16(*)[200])(smem);          // 64 x 200 (aliases Qs+Ks after barrier)
  u16 (*Vt)[200] = (u16(*)[200])(smem + 16896);  // 64 x 200 (V transposed: [d][key])

  // stage Q (reg path, padded rows)
  #pragma unroll
  for (int i = 0; i < 2; ++i){
    int cid = tid + 256*i; int r = cid >> 3, c = cid & 7;
    *(i32x4*)&Qs[r][c*8] = *(const i32x4*)(qkv + (size_t)(q0 + r)*D3 + h*64 + c*8);
  }
  // stage K via global_load_lds (unconditional; OOB rows masked post-MFMA)
  {
    const int rsubK = l >> 3;                    // row within 8-row chunk
    const int csrcK = ((l & 7) ^ rsubK) * 8;     // swizzled source col
    #pragma unroll
    for (int i = 0; i < 6; ++i){
      const int ca = w*6 + i;                    // 0..23 chunks (8 rows x 64 cols)
      const long kj = (long)(q0 - 64 + ca*8 + rsubK);
      __builtin_amdgcn_global_load_lds(
        (const AS1 void*)(qkv + kj*D3 + 1024 + h*64 + csrcK),
        (AS3 void*)(Ks + ca*512), 16, 0, 0);
    }
  }
  // stage V transposed (reg path, conditional zero)
  #pragma unroll
  for (int i = 0; i < 6; ++i){
    int cid = tid + 256*i; int r = cid >> 3, c = cid & 7;
    int kj = q0 - 64 + r;
    i32x4 vv = {0,0,0,0};
    if (kj >= 0 && kj < S)
      vv = *(const i32x4*)(qkv + (size_t)kj*D3 + 2048 + h*64 + c*8);
    union { i32x4 v; u16 u[8]; } uu; uu.v = vv;
    #pragma unroll
    for (int j = 0; j < 8; ++j) Vt[c*8 + j][r] = uu.u[j];
  }
  __syncthreads();

  f32x4 sc[12];
  #pragma unroll
  for (int cf = 0; cf < 12; ++cf) sc[cf] = (f32x4){0.f,0.f,0.f,0.f};
  const int ko = l4 * 8;
  const int swzK = (l15 & 7) * 8;
  short8 a0 = *(const short8*)&Qs[16*w + l15][ko];
  short8 a1 = *(const short8*)&Qs[16*w + l15][32 + ko];
  #pragma unroll
  for (int cf = 0; cf < 12; ++cf){
    short8 b0 = *(const short8*)&Ks[(cf*16 + l15)*64 + (ko ^ swzK)];
    short8 b1 = *(const short8*)&Ks[(cf*16 + l15)*64 + ((32 + ko) ^ swzK)];
    sc[cf] = __builtin_amdgcn_mfma_f32_16x16x32_bf16(a0, b0, sc[cf], 0, 0, 0);
    sc[cf] = __builtin_amdgcn_mfma_f32_16x16x32_bf16(a1, b1, sc[cf], 0, 0, 0);
  }
  __syncthreads();   // all waves done with Qs/Ks -> Ps (alias) writable

  const float scale = 0.125f;
  #pragma unroll
  for (int r = 0; r < 4; ++r){
    const int qrl = 16*w + l4*4 + r;
    float mx = -1e30f;
    #pragma unroll
    for (int cf = 0; cf < 12; ++cf){
      int j  = cf*16 + l15;
      int kj = q0 - 64 + j;
      bool ok = (j >= qrl) && (j <= qrl + 128) && (kj >= 0) && (kj < S);
      float sv = ok ? sc[cf][r]*scale : -1e30f;
      sc[cf][r] = sv;
      mx = fmaxf(mx, sv);
    }
    #pragma unroll
    for (int off = 1; off < 16; off <<= 1) mx = fmaxf(mx, __shfl_xor(mx, off, 64));
    float sm = 0.f;
    #pragma unroll
    for (int cf = 0; cf < 12; ++cf){
      float pv = __expf(sc[cf][r] - mx);
      sc[cf][r] = pv;
      sm += pv;
    }
    #pragma unroll
    for (int off = 1; off < 16; off <<= 1) sm += __shfl_xor(sm, off, 64);
    float inv = 1.0f / sm;
    #pragma unroll
    for (int cf = 0; cf < 12; ++cf) Ps[qrl][cf*16 + l15] = f2bf(sc[cf][r] * inv);
  }
  __syncthreads();

  f32x4 o[4];
  #pragma unroll
  for (int df = 0; df < 4; ++df) o[df] = (f32x4){0.f,0.f,0.f,0.f};
  #pragma unroll
  for (int kk = 0; kk < 6; ++kk){
    short8 a = *(const short8*)&Ps[16*w + l15][kk*32 + ko];
    #pragma unroll
    for (int df = 0; df < 4; ++df){
      short8 b = *(const short8*)&Vt[df*16 + l15][kk*32 + ko];
      o[df] = __builtin_amdgcn_mfma_f32_16x16x32_bf16(a, b, o[df], 0, 0, 0);
    }
  }
  #pragma unroll
  for (int df = 0; df < 4; ++df){
    #pragma unroll
    for (int r = 0; r < 4; ++r){
      attn_out[(size_t)(q0 + 16*w + l4*4 + r)*1024 + h*64 + df*16 + l15] = f2bf(o[df][r]);
    }
  }
}

extern "C" void kernel_launch(void* const* d_in, const int* in_sizes, int n_in,
                              void* d_out, int out_size, void* d_ws, size_t ws_size,
                              hipStream_t stream)
{
  const float* x     = (const float*)d_in[0];
  const float* qkv_w = (const float*)d_in[1];
  const float* out_w = (const float*)d_in[2];
  const float* ln_g  = (const float*)d_in[3];
  const float* ln_b  = (const float*)d_in[4];
  const float* w1    = (const float*)d_in[5];
  const float* b1    = (const float*)d_in[6];
  const float* w2    = (const float*)d_in[7];
  const float* b2    = (const float*)d_in[8];
  float* out_final = (float*)d_out;

  // Layout: first 33.55 MB is buffers all dead by FFN2 -> reused as 4 f32 partials.
  char* p = (char*)d_ws;
  u16* xn_b   = (u16*)p; p += (size_t)2048*1024*2;   // dead after QKV
  u16* qkv_b  = (u16*)p; p += (size_t)2048*3072*2;   // dead after attn
  u16* attn_b = (u16*)p; p += (size_t)2048*1024*2;   // dead after out-proj
  u16* out_b  = (u16*)p; p += (size_t)2048*1024*2;   // live until reduce (bf16 residual)
  u16* qkvw_b = (u16*)p; p += (size_t)3072*1024*2;   // dead after QKV
  u16* outw_b = (u16*)p; p += (size_t)1024*1024*2;   // dead after out-proj
  u16* w1_b   = (u16*)p; p += (size_t)4096*1024*2;
  u16* w2_b   = (u16*)p; p += (size_t)1024*4096*2;
  u16* h_b    = (u16*)p; p += (size_t)2048*4096*2;

  // partials must NOT overlap out_b (read by reduce): use xn+qkv+attn (16MB+... = 25.2MB)
  // + qkvw (6.3MB) -> but that span includes out_b. Place partials over xn_b..attn_b +
  // qkvw_b..outw_b is non-contiguous; instead put partials AFTER h_b (plenty of ws).
  float* partials = (float*)p;                       // 4 x 2048x1024 f32 = 33.55 MB

  // fused LN + weight converts (2048 LN blocks + 12288 convert blocks)
  prep_kernel<<<14336, 256, 0, stream>>>(x, ln_g, ln_b, xn_b,
                                         qkv_w, qkvw_b, out_w, outw_b,
                                         w1, w1_b, w2, w2_b);
  // QKV projection: [2048,1024] x [3072,1024]^T -> bf16 [2048,3072]  (16x48 = 768 blocks, 3/CU)
  gemm_lds<0,64><<<dim3(768), 256, 0, stream>>>(xn_b, qkvw_b, nullptr, qkv_b, nullptr, nullptr,
                                                2048, 3072, 1024, 48, 768, 1024);
  // local attention -> bf16 [2048,1024]
  attn_kernel<<<dim3(32,16), 256, 0, stream>>>(qkv_b, attn_b);
  // out projection + residual(x) -> bf16 out_b  (16x16 = 256 blocks)
  gemm_lds<1,64><<<dim3(256), 256, 0, stream>>>(attn_b, outw_b, nullptr, out_b, nullptr, x,
                                                2048, 1024, 1024, 16, 256, 1024);
  // FFN1 + bias + GELU -> h bf16 [2048,4096]  (16x32 = 512 blocks, 2/CU)
  gemm_lds<2,128><<<dim3(512), 256, 0, stream>>>(out_b, w1_b, nullptr, h_b, b1, nullptr,
                                                 2048, 4096, 1024, 32, 512, 1024);
  // FFN2 split-K=4 partials -> f32  (16x8 xy * 4 z = 512 blocks, 2/CU)
  gemm_lds<4,128><<<dim3(128, 4), 256, 0, stream>>>(h_b, w2_b, partials, nullptr, nullptr, nullptr,
                                                    2048, 1024, 4096, 8, 128, 1024);
  // reduce: out = p0+p1+p2+p3 + b2 + bf16(out)
  reduce_ffn2<<<2048, 256, 0, stream>>>(partials, b2, out_b, out_final);
}

// Round 8
// 116.957 us; speedup vs baseline: 1.2565x; 1.0611x over previous
//
#include <hip/hip_runtime.h>
#include <math.h>

typedef unsigned short u16;
typedef __attribute__((ext_vector_type(8))) short short8;
typedef __attribute__((ext_vector_type(4))) float f32x4;
typedef __attribute__((ext_vector_type(4))) int i32x4;
typedef __attribute__((ext_vector_type(4))) u16 u16x4;

#define AS1 __attribute__((address_space(1)))
#define AS3 __attribute__((address_space(3)))

__device__ inline u16 f2bf(float f){
  union { float f; unsigned int u; } x; x.f = f;
  unsigned int r = x.u + 0x7fffu + ((x.u >> 16) & 1u);
  return (u16)(r >> 16);
}
__device__ inline float bf2f(u16 u){
  union { unsigned int u; float f; } x; x.u = ((unsigned int)u) << 16;
  return x.f;
}
// exact-GELU via tanh form (max dev ~3e-4, far below bf16 rounding of h)
__device__ inline float gelu_fast(float v){
  float y = 0.7978845608f * (v + 0.044715f * v * v * v);
  float e = __expf(2.0f * y);
  return v - v / (e + 1.0f);          // = 0.5 v (1 + tanh y); e=inf -> v, e=0 -> 0
}

// ---------------- fused prep: LayerNorm (blocks 0..2047) + 4 weight converts ----------------
__global__ __launch_bounds__(256) void prep_kernel(
    const float* __restrict__ x, const float* __restrict__ g, const float* __restrict__ b,
    u16* __restrict__ xn,
    const float* __restrict__ qkv_w, u16* __restrict__ qkvw_b,
    const float* __restrict__ out_w, u16* __restrict__ outw_b,
    const float* __restrict__ w1,    u16* __restrict__ w1_b,
    const float* __restrict__ w2,    u16* __restrict__ w2_b)
{
  const int tid = threadIdx.x;
  int bid = blockIdx.x;
  if (bid < 2048){
    const int row = bid;
    float4 v = *(const float4*)(x + (size_t)row*1024 + tid*4);
    float s  = v.x + v.y + v.z + v.w;
    float ss = v.x*v.x + v.y*v.y + v.z*v.z + v.w*v.w;
    #pragma unroll
    for (int off = 32; off; off >>= 1){
      s  += __shfl_xor(s,  off, 64);
      ss += __shfl_xor(ss, off, 64);
    }
    __shared__ float red[8];
    const int wid = tid >> 6;
    if ((tid & 63) == 0){ red[wid] = s; red[4+wid] = ss; }
    __syncthreads();
    float S  = red[0]+red[1]+red[2]+red[3];
    float SS = red[4]+red[5]+red[6]+red[7];
    float mu  = S * (1.0f/1024.0f);
    float var = SS * (1.0f/1024.0f) - mu*mu;
    float rs  = rsqrtf(var + 1e-5f);
    float4 gv = *(const float4*)(g + tid*4);
    float4 bv = *(const float4*)(b + tid*4);
    u16x4 pk;
    pk.x = f2bf((v.x-mu)*rs*gv.x + bv.x);
    pk.y = f2bf((v.y-mu)*rs*gv.y + bv.y);
    pk.z = f2bf((v.z-mu)*rs*gv.z + bv.z);
    pk.w = f2bf((v.w-mu)*rs*gv.w + bv.w);
    *(u16x4*)(xn + (size_t)row*1024 + tid*4) = pk;
    return;
  }
  bid -= 2048;
  const float* src; u16* dst;
  if (bid < 3072){ src = qkv_w; dst = qkvw_b; }
  else if (bid < 3072+1024){ src = out_w; dst = outw_b; bid -= 3072; }
  else if (bid < 3072+1024+4096){ src = w1; dst = w1_b; bid -= 3072+1024; }
  else { src = w2; dst = w2_b; bid -= 3072+1024+4096; }
  const size_t i = ((size_t)bid*256 + tid) * 4;
  float4 v = *(const float4*)(src + i);
  u16x4 pk;
  pk.x = f2bf(v.x); pk.y = f2bf(v.y); pk.z = f2bf(v.z); pk.w = f2bf(v.w);
  *(u16x4*)(dst + i) = pk;
}

// ---------------- GEMM: BMxBN block, WAVES waves, double-buffered 2-phase ----------------
// C[M,N] = A[M,K] * B[N,K]^T. global_load_lds width=16, linear LDS dest,
// bank-swizzle via pre-swizzled global SOURCE col: LDS[row][c] = G[row][c ^ (row&7)*8].
// WAVES=8: wave grid 4x2 (wave tile BM/4 x BN/2); WAVES=4: 2x2 (BM/2 x BN/2).
// EPI 0: bf16 | EPI 1: +resid(f32) -> bf16 | EPI 2: +bias,GELU -> bf16
// EPI 4: split-K bf16 partial at outB + kz*M*N
template<int EPI, int BM, int BN, int WAVES>
__global__ __launch_bounds__(WAVES*64) void gemm_lds(
    const u16* __restrict__ A, const u16* __restrict__ B,
    float* __restrict__ outF, u16* __restrict__ outB,
    const float* __restrict__ bias, const float* __restrict__ resid,
    int M, int N, int K, int nbx, int nwg, int Kc)
{
  constexpr int WR  = (WAVES == 8) ? 4 : 2;
  constexpr int WC  = 2;
  constexpr int MI  = BM / WR / 16;        // M-frags per wave
  constexpr int NJ  = BN / WC / 16;        // N-frags per wave
  constexpr int ACH = BM / 8 / WAVES;      // A staging chunks per wave
  constexpr int BCH = BN / 8 / WAVES;      // B staging chunks per wave
  __shared__ u16 As[2][BM*64];
  __shared__ u16 Bs[2][BN*64];
  const int tid = threadIdx.x;
  const int l   = tid & 63;
  const int w   = tid >> 6;
  const int wr  = w & (WR-1), wc = w / WR;
  const int orig = blockIdx.x;
  const int wgid = (orig & 7) * (nwg >> 3) + (orig >> 3);   // XCD-contiguous (nwg%8==0)
  const int bcol = wgid % nbx, brow = wgid / nbx;
  const int kz = blockIdx.y;
  const int l15 = l & 15, l4 = l >> 4;

  const u16* Ab = A + (size_t)brow*BM*K + (size_t)kz*Kc;
  const u16* Bb = B + (size_t)bcol*BN*K + (size_t)kz*Kc;

  f32x4 acc[MI][NJ];
  #pragma unroll
  for (int i = 0; i < MI; ++i)
    #pragma unroll
    for (int j = 0; j < NJ; ++j)
      acc[i][j] = (f32x4){0.f, 0.f, 0.f, 0.f};

  const int rsub = l >> 3;                       // 0..7 (row & 7 of this lane's slot)
  const int csrc = ((l & 7) ^ rsub) * 8;         // swizzled source col (elements)
  const int swz  = (l15 & 7) * 8;                // read-side unswizzle
  const int nkt = Kc >> 6;

  auto stage = [&](int kt, int buf){
    const u16* Ag = Ab + kt*64 + csrc;
    const u16* Bg = Bb + kt*64 + csrc;
    #pragma unroll
    for (int i = 0; i < ACH; ++i){
      const int ca = w*ACH + i;                  // 0..BM/8-1 (8 rows x 64 cols)
      __builtin_amdgcn_global_load_lds(
        (const AS1 void*)(Ag + (size_t)(ca*8 + rsub)*K),
        (AS3 void*)(&As[buf][ca*512]), 16, 0, 0);
    }
    #pragma unroll
    for (int i = 0; i < BCH; ++i){
      const int cb = w*BCH + i;                  // 0..BN/8-1
      __builtin_amdgcn_global_load_lds(
        (const AS1 void*)(Bg + (size_t)(cb*8 + rsub)*K),
        (AS3 void*)(&Bs[buf][cb*512]), 16, 0, 0);
    }
  };

  stage(0, 0);
  __syncthreads();                               // tile 0 ready
  for (int kt = 0; kt < nkt; ++kt){
    const int cur = kt & 1;
    if (kt + 1 < nkt) stage(kt + 1, cur ^ 1);    // issue next-tile loads FIRST
    #pragma unroll
    for (int ks = 0; ks < 2; ++ks){              // compute current tile
      const int kop = (ks*32 + l4*8) ^ swz;
      short8 af[MI], bfr[NJ];
      #pragma unroll
      for (int i = 0; i < MI; ++i)
        af[i]  = *(const short8*)&As[cur][(wr*(BM/WR) + i*16 + l15)*64 + kop];
      #pragma unroll
      for (int j = 0; j < NJ; ++j)
        bfr[j] = *(const short8*)&Bs[cur][(wc*(BN/WC) + j*16 + l15)*64 + kop];
      #pragma unroll
      for (int i = 0; i < MI; ++i)
        #pragma unroll
        for (int j = 0; j < NJ; ++j)
          acc[i][j] = __builtin_amdgcn_mfma_f32_16x16x32_bf16(af[i], bfr[j], acc[i][j], 0, 0, 0);
    }
    __syncthreads();                             // next tile staged + cur reads done
  }

  #pragma unroll
  for (int i = 0; i < MI; ++i){
    #pragma unroll
    for (int j = 0; j < NJ; ++j){
      #pragma unroll
      for (int r = 0; r < 4; ++r){
        int row = brow*BM + wr*(BM/WR) + i*16 + l4*4 + r;
        int col = bcol*BN + wc*(BN/WC) + j*16 + l15;
        float v = acc[i][j][r];
        size_t o = (size_t)row * N + col;
        if constexpr (EPI == 0){
          outB[o] = f2bf(v);
        } else if constexpr (EPI == 1){
          v += resid[o];
          outB[o] = f2bf(v);
        } else if constexpr (EPI == 2){
          v += bias[col];
          outB[o] = f2bf(gelu_fast(v));
        } else {  // EPI == 4: split-K bf16 partial
          outB[(size_t)kz * M * N + o] = f2bf(v);
        }
      }
    }
  }
}

// ---------------- FFN2 split-K=4 reduce: out = p0+p1+p2+p3 (bf16) + bias + resid(bf16) -----
__global__ __launch_bounds__(256) void reduce_ffn2(const u16* __restrict__ p,
                                                   const float* __restrict__ bias,
                                                   const u16* __restrict__ resid_b,
                                                   float* __restrict__ out){
  const size_t s = (size_t)2048*1024;
  const size_t i = ((size_t)blockIdx.x * 256 + threadIdx.x) * 4;
  u16x4 a0 = *(const u16x4*)(p + i);
  u16x4 a1 = *(const u16x4*)(p + s + i);
  u16x4 a2 = *(const u16x4*)(p + 2*s + i);
  u16x4 a3 = *(const u16x4*)(p + 3*s + i);
  u16x4 rb = *(const u16x4*)(resid_b + i);
  float4 bb = *(const float4*)(bias + (i & 1023));
  float4 o;
  o.x = bf2f(a0.x) + bf2f(a1.x) + bf2f(a2.x) + bf2f(a3.x) + bf2f(rb.x) + bb.x;
  o.y = bf2f(a0.y) + bf2f(a1.y) + bf2f(a2.y) + bf2f(a3.y) + bf2f(rb.y) + bb.y;
  o.z = bf2f(a0.z) + bf2f(a1.z) + bf2f(a2.z) + bf2f(a3.z) + bf2f(rb.z) + bb.z;
  o.w = bf2f(a0.w) + bf2f(a1.w) + bf2f(a2.w) + bf2f(a3.w) + bf2f(rb.w) + bb.w;
  *(float4*)(out + i) = o;
}

// ---------------- Local-window attention ----------------
// K staged via global_load_lds into linear [192][64] with source swizzle (row&7);
// K rows outside [0,S) read adjacent ws garbage but are masked AFTER QK^T (value replaced).
// V keeps conditional zero-fill (P=0 x garbage-inf would NaN through MFMA).
__global__ __launch_bounds__(256) void attn_kernel(const u16* __restrict__ qkv, u16* __restrict__ attn_out){
  constexpr int S = 2048, D3 = 3072;
  const int qt = blockIdx.x, h = blockIdx.y;
  const int q0 = qt * 64;
  const int tid = threadIdx.x;
  const int l = tid & 63, w = tid >> 6;
  const int l15 = l & 15, l4 = l >> 4;

  __shared__ u16 smem[29696];                    // 59392 B
  u16 (*Qs)[72]  = (u16(*)[72]) (smem);          // 64 x 72 (padded, reg-staged)
  u16 *Ks        = smem + 4608;                  // 192 x 64 linear (gload_lds, swizzled)
  u16 (*Ps)[200] = (u16(*)[200])(smem);          // 64 x 200 (aliases Qs+Ks after barrier)
  u16 (*Vt)[200] = (u16(*)[200])(smem + 16896);  // 64 x 200 (V transposed: [d][key])

  // stage Q (reg path, padded rows)
  #pragma unroll
  for (int i = 0; i < 2; ++i){
    int cid = tid + 256*i; int r = cid >> 3, c = cid & 7;
    *(i32x4*)&Qs[r][c*8] = *(const i32x4*)(qkv + (size_t)(q0 + r)*D3 + h*64 + c*8);
  }
  // stage K via global_load_lds (unconditional; OOB rows masked post-MFMA)
  {
    const int rsubK = l >> 3;                    // row within 8-row chunk
    const int csrcK = ((l & 7) ^ rsubK) * 8;     // swizzled source col
    #pragma unroll
    for (int i = 0; i < 6; ++i){
      const int ca = w*6 + i;                    // 0..23 chunks (8 rows x 64 cols)
      const long kj = (long)(q0 - 64 + ca*8 + rsubK);
      __builtin_amdgcn_global_load_lds(
        (const AS1 void*)(qkv + kj*D3 + 1024 + h*64 + csrcK),
        (AS3 void*)(Ks + ca*512), 16, 0, 0);
    }
  }
  // stage V transposed (reg path, conditional zero)
  #pragma unroll
  for (int i = 0; i < 6; ++i){
    int cid = tid + 256*i; int r = cid >> 3, c = cid & 7;
    int kj = q0 - 64 + r;
    i32x4 vv = {0,0,0,0};
    if (kj >= 0 && kj < S)
      vv = *(const i32x4*)(qkv + (size_t)kj*D3 + 2048 + h*64 + c*8);
    union { i32x4 v; u16 u[8]; } uu; uu.v = vv;
    #pragma unroll
    for (int j = 0; j < 8; ++j) Vt[c*8 + j][r] = uu.u[j];
  }
  __syncthreads();

  f32x4 sc[12];
  #pragma unroll
  for (int cf = 0; cf < 12; ++cf) sc[cf] = (f32x4){0.f,0.f,0.f,0.f};
  const int ko = l4 * 8;
  const int swzK = (l15 & 7) * 8;
  short8 a0 = *(const short8*)&Qs[16*w + l15][ko];
  short8 a1 = *(const short8*)&Qs[16*w + l15][32 + ko];
  #pragma unroll
  for (int cf = 0; cf < 12; ++cf){
    short8 b0 = *(const short8*)&Ks[(cf*16 + l15)*64 + (ko ^ swzK)];
    short8 b1 = *(const short8*)&Ks[(cf*16 + l15)*64 + ((32 + ko) ^ swzK)];
    sc[cf] = __builtin_amdgcn_mfma_f32_16x16x32_bf16(a0, b0, sc[cf], 0, 0, 0);
    sc[cf] = __builtin_amdgcn_mfma_f32_16x16x32_bf16(a1, b1, sc[cf], 0, 0, 0);
  }
  __syncthreads();   // all waves done with Qs/Ks -> Ps (alias) writable

  const float scale = 0.125f;
  #pragma unroll
  for (int r = 0; r < 4; ++r){
    const int qrl = 16*w + l4*4 + r;
    float mx = -1e30f;
    #pragma unroll
    for (int cf = 0; cf < 12; ++cf){
      int j  = cf*16 + l15;
      int kj = q0 - 64 + j;
      bool ok = (j >= qrl) && (j <= qrl + 128) && (kj >= 0) && (kj < S);
      float sv = ok ? sc[cf][r]*scale : -1e30f;
      sc[cf][r] = sv;
      mx = fmaxf(mx, sv);
    }
    #pragma unroll
    for (int off = 1; off < 16; off <<= 1) mx = fmaxf(mx, __shfl_xor(mx, off, 64));
    float sm = 0.f;
    #pragma unroll
    for (int cf = 0; cf < 12; ++cf){
      float pv = __expf(sc[cf][r] - mx);
      sc[cf][r] = pv;
      sm += pv;
    }
    #pragma unroll
    for (int off = 1; off < 16; off <<= 1) sm += __shfl_xor(sm, off, 64);
    float inv = 1.0f / sm;
    #pragma unroll
    for (int cf = 0; cf < 12; ++cf) Ps[qrl][cf*16 + l15] = f2bf(sc[cf][r] * inv);
  }
  __syncthreads();

  f32x4 o[4];
  #pragma unroll
  for (int df = 0; df < 4; ++df) o[df] = (f32x4){0.f,0.f,0.f,0.f};
  #pragma unroll
  for (int kk = 0; kk < 6; ++kk){
    short8 a = *(const short8*)&Ps[16*w + l15][kk*32 + ko];
    #pragma unroll
    for (int df = 0; df < 4; ++df){
      short8 b = *(const short8*)&Vt[df*16 + l15][kk*32 + ko];
      o[df] = __builtin_amdgcn_mfma_f32_16x16x32_bf16(a, b, o[df], 0, 0, 0);
    }
  }
  #pragma unroll
  for (int df = 0; df < 4; ++df){
    #pragma unroll
    for (int r = 0; r < 4; ++r){
      attn_out[(size_t)(q0 + 16*w + l4*4 + r)*1024 + h*64 + df*16 + l15] = f2bf(o[df][r]);
    }
  }
}

extern "C" void kernel_launch(void* const* d_in, const int* in_sizes, int n_in,
                              void* d_out, int out_size, void* d_ws, size_t ws_size,
                              hipStream_t stream)
{
  const float* x     = (const float*)d_in[0];
  const float* qkv_w = (const float*)d_in[1];
  const float* out_w = (const float*)d_in[2];
  const float* ln_g  = (const float*)d_in[3];
  const float* ln_b  = (const float*)d_in[4];
  const float* w1    = (const float*)d_in[5];
  const float* b1    = (const float*)d_in[6];
  const float* w2    = (const float*)d_in[7];
  const float* b2    = (const float*)d_in[8];
  float* out_final = (float*)d_out;

  char* p = (char*)d_ws;
  u16* xn_b   = (u16*)p; p += (size_t)2048*1024*2;   // dead after QKV
  u16* qkv_b  = (u16*)p; p += (size_t)2048*3072*2;   // dead after attn
  u16* attn_b = (u16*)p; p += (size_t)2048*1024*2;   // dead after out-proj
  u16* out_b  = (u16*)p; p += (size_t)2048*1024*2;   // live until reduce (bf16 residual)
  u16* qkvw_b = (u16*)p; p += (size_t)3072*1024*2;   // dead after QKV
  u16* outw_b = (u16*)p; p += (size_t)1024*1024*2;   // dead after out-proj
  u16* w1_b   = (u16*)p; p += (size_t)4096*1024*2;
  u16* w2_b   = (u16*)p; p += (size_t)1024*4096*2;
  u16* h_b    = (u16*)p; p += (size_t)2048*4096*2;
  u16* partials = (u16*)p;                           // 4 x 2048x1024 bf16 = 16.8 MB

  // fused LN + weight converts (2048 LN blocks + 12288 convert blocks)
  prep_kernel<<<14336, 256, 0, stream>>>(x, ln_g, ln_b, xn_b,
                                         qkv_w, qkvw_b, out_w, outw_b,
                                         w1, w1_b, w2, w2_b);
  // QKV: [2048,1024] x [3072,1024]^T -> bf16  (16x48 = 768 blocks, 3/CU, 8 waves = 24 w/CU)
  gemm_lds<0,128,64,8><<<dim3(768), 512, 0, stream>>>(xn_b, qkvw_b, nullptr, qkv_b, nullptr, nullptr,
                                                      2048, 3072, 1024, 48, 768, 1024);
  // local attention -> bf16 [2048,1024]
  attn_kernel<<<dim3(32,16), 256, 0, stream>>>(qkv_b, attn_b);
  // out projection + residual(x) -> bf16 out_b  (32x16 = 512 blocks, 2/CU, 4 waves)
  gemm_lds<1,64,64,4><<<dim3(512), 256, 0, stream>>>(attn_b, outw_b, nullptr, out_b, nullptr, x,
                                                     2048, 1024, 1024, 16, 512, 1024);
  // FFN1 + bias + GELU -> h bf16  (16x32 = 512 blocks, 2/CU, 8 waves = 16 w/CU)
  gemm_lds<2,128,128,8><<<dim3(512), 512, 0, stream>>>(out_b, w1_b, nullptr, h_b, b1, nullptr,
                                                       2048, 4096, 1024, 32, 512, 1024);
  // FFN2 split-K=4 bf16 partials  (16x8 xy * 4 z = 512 blocks, 2/CU, 8 waves)
  gemm_lds<4,128,128,8><<<dim3(128, 4), 512, 0, stream>>>(h_b, w2_b, nullptr, partials, nullptr, nullptr,
                                                          2048, 1024, 4096, 8, 128, 1024);
  // reduce: out = p0+p1+p2+p3 + b2 + bf16(out)
  reduce_ffn2<<<2048, 256, 0, stream>>>(partials, b2, out_b, out_final);
}